// Round 2
// baseline (658.867 us; speedup 1.0000x reference)
//
#include <hip/hip_runtime.h>
#include <stdint.h>
#include <math.h>

#define N_NODES   100000
#define N_EDGES   1600000
#define NFEAT     100
#define HIDDEN    32
#define OUTC      2

#define SCAN_B    1024
#define CHUNK     98    // ceil(100000/1024)

// ---------------------------------------------------------------------------
// JAX threefry2x32, key=(0,42), partitionable scheme: bits(f) = o0^o1 of
// threefry2x32((0,42),(0,f)); uniform = bitcast((bits>>9)|0x3f800000)-1 < 0.8
// ---------------------------------------------------------------------------
__device__ __forceinline__ uint32_t rotl32(uint32_t x, int r) {
    return (x << r) | (x >> (32 - r));
}

__device__ __forceinline__ uint32_t threefry_bits(uint32_t f) {
    const uint32_t ks0 = 0u;
    const uint32_t ks1 = 42u;
    const uint32_t ks2 = 0x1BD11BDAu ^ 0u ^ 42u;
    uint32_t x0 = 0u + ks0;
    uint32_t x1 = f  + ks1;
#define TF_ROUND(r) { x0 += x1; x1 = rotl32(x1, (r)); x1 ^= x0; }
    TF_ROUND(13) TF_ROUND(15) TF_ROUND(26) TF_ROUND(6)
    x0 += ks1; x1 += ks2 + 1u;
    TF_ROUND(17) TF_ROUND(29) TF_ROUND(16) TF_ROUND(24)
    x0 += ks2; x1 += ks0 + 2u;
    TF_ROUND(13) TF_ROUND(15) TF_ROUND(26) TF_ROUND(6)
    x0 += ks0; x1 += ks1 + 3u;
    TF_ROUND(17) TF_ROUND(29) TF_ROUND(16) TF_ROUND(24)
    x0 += ks1; x1 += ks2 + 4u;
    TF_ROUND(13) TF_ROUND(15) TF_ROUND(26) TF_ROUND(6)
    x0 += ks2; x1 += ks0 + 5u;
#undef TF_ROUND
    return x0 ^ x1;
}

__device__ __forceinline__ bool dropout_keep(uint32_t f) {
    uint32_t bits = threefry_bits(f);
    float u = __uint_as_float((bits >> 9) | 0x3f800000u) - 1.0f;
    return u < 0.8f;
}

// ---------------------------------------------------------------------------
// 1. Degree histogram over dst (int atomics)
// ---------------------------------------------------------------------------
__global__ __launch_bounds__(256) void k_deg(const int* __restrict__ dst,
                                             int* __restrict__ cnt) {
    int e = blockIdx.x * 256 + threadIdx.x;
    if (e < N_EDGES) atomicAdd(&cnt[dst[e]], 1);
}

// ---------------------------------------------------------------------------
// 2. Single-block exclusive scan cnt -> rowptr, plus dinv = rsqrt(deg+1)
// ---------------------------------------------------------------------------
__global__ __launch_bounds__(SCAN_B) void k_scan(const int* __restrict__ cnt,
                                                 int* __restrict__ rowptr,
                                                 float* __restrict__ dinv) {
    __shared__ int lds[SCAN_B];
    const int t = threadIdx.x;
    const int base = t * CHUNK;
    int mysum = 0;
    for (int i = 0; i < CHUNK; ++i) {
        int idx = base + i;
        if (idx < N_NODES) mysum += cnt[idx];
    }
    lds[t] = mysum;
    __syncthreads();
    for (int off = 1; off < SCAN_B; off <<= 1) {
        int v = (t >= off) ? lds[t - off] : 0;
        __syncthreads();
        lds[t] += v;
        __syncthreads();
    }
    int running = lds[t] - mysum;  // exclusive prefix of this chunk
    for (int i = 0; i < CHUNK; ++i) {
        int idx = base + i;
        if (idx < N_NODES) {
            int c = cnt[idx];
            rowptr[idx] = running;
            running += c;
            dinv[idx] = rsqrtf((float)(c + 1));
        }
    }
    if (t == SCAN_B - 1) rowptr[N_NODES] = lds[SCAN_B - 1];
}

// ---------------------------------------------------------------------------
// 3. Scatter edges into CSR order (int atomics on fill cursors)
// ---------------------------------------------------------------------------
__global__ __launch_bounds__(256) void k_scatter(const int* __restrict__ src,
                                                 const int* __restrict__ dst,
                                                 const int* __restrict__ rowptr,
                                                 int* __restrict__ fill,
                                                 int* __restrict__ csr_src) {
    int e = blockIdx.x * 256 + threadIdx.x;
    if (e >= N_EDGES) return;
    int d = dst[e];
    int pos = rowptr[d] + atomicAdd(&fill[d], 1);
    csr_src[pos] = src[e];
}

// ---------------------------------------------------------------------------
// 4. h0 = x @ W1  [N,100]@[100,32]; 8 rows per 256-thread block
// ---------------------------------------------------------------------------
__global__ __launch_bounds__(256) void k_gemm1(const float* __restrict__ x,
                                               const float* __restrict__ W1,
                                               float* __restrict__ h0) {
    __shared__ float w1s[NFEAT * HIDDEN];
    __shared__ float xs[8][NFEAT];
    const int tid = threadIdx.x;
    for (int i = tid; i < NFEAT * HIDDEN; i += 256) w1s[i] = W1[i];
    const int row0 = blockIdx.x * 8;
    const float* xb = x + (size_t)row0 * NFEAT;
    for (int i = tid; i < 8 * NFEAT; i += 256) xs[i / NFEAT][i % NFEAT] = xb[i];
    __syncthreads();
    const int r = tid >> 5, c = tid & 31;
    float acc = 0.0f;
#pragma unroll 4
    for (int k = 0; k < NFEAT; ++k)
        acc = fmaf(xs[r][k], w1s[k * HIDDEN + c], acc);
    h0[(size_t)(row0 + r) * HIDDEN + c] = acc;
}

// ---------------------------------------------------------------------------
// 5. Layer 1 fused: CSR aggregation + self-loop + b1 + ReLU + dropout + @W2
//    One 32-lane group per node; lane c owns column c.
// ---------------------------------------------------------------------------
__global__ __launch_bounds__(256) void k_layer1(const int* __restrict__ rowptr,
                                                const int* __restrict__ csr_src,
                                                const float* __restrict__ dinv,
                                                const float* __restrict__ h0,
                                                const float* __restrict__ b1,
                                                const float* __restrict__ W2,
                                                float* __restrict__ h2) {
    int t = blockIdx.x * 256 + threadIdx.x;
    int n = t >> 5;
    int c = t & 31;
    if (n >= N_NODES) return;
    float din = dinv[n];
    float acc = h0[(size_t)n * HIDDEN + c] * din * din;  // self loop
    int beg = rowptr[n], end = rowptr[n + 1];
    for (int j = beg; j < end; ++j) {
        int s = csr_src[j];
        acc = fmaf(h0[(size_t)s * HIDDEN + c], dinv[s] * din, acc);
    }
    float v = fmaxf(acc + b1[c], 0.0f);
    v = dropout_keep((uint32_t)(n * HIDDEN + c)) ? v * 1.25f : 0.0f;
    float p0 = v * W2[c * 2 + 0];
    float p1 = v * W2[c * 2 + 1];
#pragma unroll
    for (int m = 16; m >= 1; m >>= 1) {
        p0 += __shfl_xor(p0, m);
        p1 += __shfl_xor(p1, m);
    }
    if (c == 0) {
        float2* o = (float2*)(h2 + (size_t)n * 2);
        *o = make_float2(p0, p1);
    }
}

// ---------------------------------------------------------------------------
// 6. Layer 2 fused: CSR aggregation + self-loop + b2 + log_softmax
//    One thread per node.
// ---------------------------------------------------------------------------
__global__ __launch_bounds__(256) void k_layer2(const int* __restrict__ rowptr,
                                                const int* __restrict__ csr_src,
                                                const float* __restrict__ dinv,
                                                const float* __restrict__ h2,
                                                const float* __restrict__ b2,
                                                float* __restrict__ out) {
    int n = blockIdx.x * 256 + threadIdx.x;
    if (n >= N_NODES) return;
    float din = dinv[n];
    float din2 = din * din;
    float2 hn = ((const float2*)h2)[n];
    float acc0 = hn.x * din2;
    float acc1 = hn.y * din2;
    int beg = rowptr[n], end = rowptr[n + 1];
    for (int j = beg; j < end; ++j) {
        int s = csr_src[j];
        float w = dinv[s] * din;
        float2 hs = ((const float2*)h2)[s];
        acc0 = fmaf(hs.x, w, acc0);
        acc1 = fmaf(hs.y, w, acc1);
    }
    float l0 = acc0 + b2[0];
    float l1 = acc1 + b2[1];
    float m = fmaxf(l0, l1);
    float lse = m + logf(expf(l0 - m) + expf(l1 - m));
    float2* o = (float2*)(out + (size_t)n * 2);
    *o = make_float2(l0 - lse, l1 - lse);
}

// ---------------------------------------------------------------------------
// Launch
// ---------------------------------------------------------------------------
static inline size_t align_up(size_t x) { return (x + 255) & ~(size_t)255; }

extern "C" void kernel_launch(void* const* d_in, const int* in_sizes, int n_in,
                              void* d_out, int out_size, void* d_ws, size_t ws_size,
                              hipStream_t stream) {
    (void)n_in; (void)in_sizes; (void)out_size; (void)ws_size;

    const float* x  = (const float*)d_in[0];
    const int*   ei = (const int*)d_in[1];
    const float* W1 = (const float*)d_in[2];
    const float* b1 = (const float*)d_in[3];
    const float* W2 = (const float*)d_in[4];
    const float* b2 = (const float*)d_in[5];
    float* out = (float*)d_out;

    const int* src = ei;
    const int* dst = ei + N_EDGES;

    char* w = (char*)d_ws;
    size_t off = 0;
    int*   cnt     = (int*)(w + off);   off += align_up((size_t)N_NODES * 4);
    int*   fill    = (int*)(w + off);   off += align_up((size_t)N_NODES * 4);
    int*   rowptr  = (int*)(w + off);   off += align_up((size_t)(N_NODES + 1) * 4);
    float* dinv    = (float*)(w + off); off += align_up((size_t)N_NODES * 4);
    int*   csr_src = (int*)(w + off);   off += align_up((size_t)N_EDGES * 4);
    float* h0      = (float*)(w + off); off += align_up((size_t)N_NODES * HIDDEN * 4);
    float* h2      = (float*)(w + off); off += align_up((size_t)N_NODES * OUTC * 4);

    // cnt and fill are adjacent -> one memset clears both
    hipMemsetAsync(cnt, 0, align_up((size_t)N_NODES * 4) + (size_t)N_NODES * 4, stream);

    const int B = 256;
    k_deg    <<<(N_EDGES + B - 1) / B, B, 0, stream>>>(dst, cnt);
    k_scan   <<<1, SCAN_B, 0, stream>>>(cnt, rowptr, dinv);
    k_scatter<<<(N_EDGES + B - 1) / B, B, 0, stream>>>(src, dst, rowptr, fill, csr_src);
    k_gemm1  <<<N_NODES / 8, B, 0, stream>>>(x, W1, h0);
    k_layer1 <<<(N_NODES * HIDDEN + B - 1) / B, B, 0, stream>>>(rowptr, csr_src, dinv, h0, b1, W2, h2);
    k_layer2 <<<(N_NODES + B - 1) / B, B, 0, stream>>>(rowptr, csr_src, dinv, h2, b2, out);
}

// Round 3
// 392.177 us; speedup vs baseline: 1.6800x; 1.6800x over previous
//
#include <hip/hip_runtime.h>
#include <stdint.h>
#include <math.h>

#define N_NODES   100000
#define N_EDGES   1600000
#define NFEAT     100
#define HIDDEN    32
#define OUTC      2

#define NB_SCAN   391   // ceil(100000/256)

// ---------------------------------------------------------------------------
// JAX threefry2x32, key=(0,42), partitionable scheme: bits(f) = o0^o1 of
// threefry2x32((0,42),(0,f)); uniform = bitcast((bits>>9)|0x3f800000)-1 < 0.8
// ---------------------------------------------------------------------------
__device__ __forceinline__ uint32_t rotl32(uint32_t x, int r) {
    return (x << r) | (x >> (32 - r));
}

__device__ __forceinline__ uint32_t threefry_bits(uint32_t f) {
    const uint32_t ks0 = 0u;
    const uint32_t ks1 = 42u;
    const uint32_t ks2 = 0x1BD11BDAu ^ 0u ^ 42u;
    uint32_t x0 = 0u + ks0;
    uint32_t x1 = f  + ks1;
#define TF_ROUND(r) { x0 += x1; x1 = rotl32(x1, (r)); x1 ^= x0; }
    TF_ROUND(13) TF_ROUND(15) TF_ROUND(26) TF_ROUND(6)
    x0 += ks1; x1 += ks2 + 1u;
    TF_ROUND(17) TF_ROUND(29) TF_ROUND(16) TF_ROUND(24)
    x0 += ks2; x1 += ks0 + 2u;
    TF_ROUND(13) TF_ROUND(15) TF_ROUND(26) TF_ROUND(6)
    x0 += ks0; x1 += ks1 + 3u;
    TF_ROUND(17) TF_ROUND(29) TF_ROUND(16) TF_ROUND(24)
    x0 += ks1; x1 += ks2 + 4u;
    TF_ROUND(13) TF_ROUND(15) TF_ROUND(26) TF_ROUND(6)
    x0 += ks2; x1 += ks0 + 5u;
#undef TF_ROUND
    return x0 ^ x1;
}

__device__ __forceinline__ bool dropout_keep(uint32_t f) {
    uint32_t bits = threefry_bits(f);
    float u = __uint_as_float((bits >> 9) | 0x3f800000u) - 1.0f;
    return u < 0.8f;
}

// ---------------------------------------------------------------------------
// 1. Degree histogram over dst (int atomics)
// ---------------------------------------------------------------------------
__global__ __launch_bounds__(256) void k_deg(const int* __restrict__ dst,
                                             int* __restrict__ cnt) {
    int e = blockIdx.x * 256 + threadIdx.x;
    if (e < N_EDGES) atomicAdd(&cnt[dst[e]], 1);
}

// ---------------------------------------------------------------------------
// 2a. Per-block inclusive scan of cnt; write block-local exclusive prefix
//     into rowptr, block total into bsum. Also dinv = rsqrt(cnt+1).
// ---------------------------------------------------------------------------
__global__ __launch_bounds__(256) void k_scan1(const int* __restrict__ cnt,
                                               int* __restrict__ rowptr,
                                               int* __restrict__ bsum,
                                               float* __restrict__ dinv) {
    __shared__ int lds[256];
    const int t = threadIdx.x;
    const int i = blockIdx.x * 256 + t;
    int c = (i < N_NODES) ? cnt[i] : 0;
    lds[t] = c;
    __syncthreads();
#pragma unroll
    for (int off = 1; off < 256; off <<= 1) {
        int v = (t >= off) ? lds[t - off] : 0;
        __syncthreads();
        lds[t] += v;
        __syncthreads();
    }
    if (i < N_NODES) {
        rowptr[i] = lds[t] - c;            // block-local exclusive
        dinv[i] = rsqrtf((float)(c + 1));
    }
    if (t == 255) bsum[blockIdx.x] = lds[255];
}

// ---------------------------------------------------------------------------
// 2b. Single small block: exclusive scan of the 391 block sums.
// ---------------------------------------------------------------------------
__global__ __launch_bounds__(512) void k_scan2(const int* __restrict__ bsum,
                                               int* __restrict__ boff,
                                               int* __restrict__ rowptr) {
    __shared__ int lds[512];
    const int t = threadIdx.x;
    int v = (t < NB_SCAN) ? bsum[t] : 0;
    lds[t] = v;
    __syncthreads();
#pragma unroll
    for (int off = 1; off < 512; off <<= 1) {
        int u = (t >= off) ? lds[t - off] : 0;
        __syncthreads();
        lds[t] += u;
        __syncthreads();
    }
    if (t < NB_SCAN) boff[t] = lds[t] - v;  // exclusive
    if (t == 0) rowptr[N_NODES] = N_EDGES;  // total is a known constant
}

// ---------------------------------------------------------------------------
// 2c. Propagate block offsets.
// ---------------------------------------------------------------------------
__global__ __launch_bounds__(256) void k_scan3(int* __restrict__ rowptr,
                                               const int* __restrict__ boff) {
    int i = blockIdx.x * 256 + threadIdx.x;
    if (i < N_NODES) rowptr[i] += boff[blockIdx.x];
}

// ---------------------------------------------------------------------------
// 3. Scatter edges into CSR order (int atomics on fill cursors)
// ---------------------------------------------------------------------------
__global__ __launch_bounds__(256) void k_scatter(const int* __restrict__ src,
                                                 const int* __restrict__ dst,
                                                 const int* __restrict__ rowptr,
                                                 int* __restrict__ fill,
                                                 int* __restrict__ csr_src) {
    int e = blockIdx.x * 256 + threadIdx.x;
    if (e >= N_EDGES) return;
    int d = dst[e];
    int pos = rowptr[d] + atomicAdd(&fill[d], 1);
    csr_src[pos] = src[e];
}

// ---------------------------------------------------------------------------
// 4. h0 = x @ W1  [N,100]@[100,32]; 8 rows per 256-thread block
// ---------------------------------------------------------------------------
__global__ __launch_bounds__(256) void k_gemm1(const float* __restrict__ x,
                                               const float* __restrict__ W1,
                                               float* __restrict__ h0) {
    __shared__ float w1s[NFEAT * HIDDEN];
    __shared__ float xs[8][NFEAT];
    const int tid = threadIdx.x;
    for (int i = tid; i < NFEAT * HIDDEN; i += 256) w1s[i] = W1[i];
    const int row0 = blockIdx.x * 8;
    const float* xb = x + (size_t)row0 * NFEAT;
    for (int i = tid; i < 8 * NFEAT; i += 256) xs[i / NFEAT][i % NFEAT] = xb[i];
    __syncthreads();
    const int r = tid >> 5, c = tid & 31;
    float acc = 0.0f;
#pragma unroll 4
    for (int k = 0; k < NFEAT; ++k)
        acc = fmaf(xs[r][k], w1s[k * HIDDEN + c], acc);
    h0[(size_t)(row0 + r) * HIDDEN + c] = acc;
}

// ---------------------------------------------------------------------------
// 5. Layer 1 fused: CSR aggregation + self-loop + b1 + ReLU + dropout + @W2
//    One 32-lane group per node; lane c owns column c.
// ---------------------------------------------------------------------------
__global__ __launch_bounds__(256) void k_layer1(const int* __restrict__ rowptr,
                                                const int* __restrict__ csr_src,
                                                const float* __restrict__ dinv,
                                                const float* __restrict__ h0,
                                                const float* __restrict__ b1,
                                                const float* __restrict__ W2,
                                                float* __restrict__ h2) {
    int t = blockIdx.x * 256 + threadIdx.x;
    int n = t >> 5;
    int c = t & 31;
    if (n >= N_NODES) return;
    float din = dinv[n];
    float acc = h0[(size_t)n * HIDDEN + c] * din * din;  // self loop
    int beg = rowptr[n], end = rowptr[n + 1];
    for (int j = beg; j < end; ++j) {
        int s = csr_src[j];
        acc = fmaf(h0[(size_t)s * HIDDEN + c], dinv[s] * din, acc);
    }
    float v = fmaxf(acc + b1[c], 0.0f);
    v = dropout_keep((uint32_t)(n * HIDDEN + c)) ? v * 1.25f : 0.0f;
    float p0 = v * W2[c * 2 + 0];
    float p1 = v * W2[c * 2 + 1];
#pragma unroll
    for (int m = 16; m >= 1; m >>= 1) {
        p0 += __shfl_xor(p0, m);
        p1 += __shfl_xor(p1, m);
    }
    if (c == 0) {
        float2* o = (float2*)(h2 + (size_t)n * 2);
        *o = make_float2(p0, p1);
    }
}

// ---------------------------------------------------------------------------
// 6. Layer 2 fused: CSR aggregation + self-loop + b2 + log_softmax
// ---------------------------------------------------------------------------
__global__ __launch_bounds__(256) void k_layer2(const int* __restrict__ rowptr,
                                                const int* __restrict__ csr_src,
                                                const float* __restrict__ dinv,
                                                const float* __restrict__ h2,
                                                const float* __restrict__ b2,
                                                float* __restrict__ out) {
    int n = blockIdx.x * 256 + threadIdx.x;
    if (n >= N_NODES) return;
    float din = dinv[n];
    float din2 = din * din;
    float2 hn = ((const float2*)h2)[n];
    float acc0 = hn.x * din2;
    float acc1 = hn.y * din2;
    int beg = rowptr[n], end = rowptr[n + 1];
    for (int j = beg; j < end; ++j) {
        int s = csr_src[j];
        float w = dinv[s] * din;
        float2 hs = ((const float2*)h2)[s];
        acc0 = fmaf(hs.x, w, acc0);
        acc1 = fmaf(hs.y, w, acc1);
    }
    float l0 = acc0 + b2[0];
    float l1 = acc1 + b2[1];
    float m = fmaxf(l0, l1);
    float lse = m + logf(expf(l0 - m) + expf(l1 - m));
    float2* o = (float2*)(out + (size_t)n * 2);
    *o = make_float2(l0 - lse, l1 - lse);
}

// ---------------------------------------------------------------------------
// Launch
// ---------------------------------------------------------------------------
static inline size_t align_up(size_t x) { return (x + 255) & ~(size_t)255; }

extern "C" void kernel_launch(void* const* d_in, const int* in_sizes, int n_in,
                              void* d_out, int out_size, void* d_ws, size_t ws_size,
                              hipStream_t stream) {
    (void)n_in; (void)in_sizes; (void)out_size; (void)ws_size;

    const float* x  = (const float*)d_in[0];
    const int*   ei = (const int*)d_in[1];
    const float* W1 = (const float*)d_in[2];
    const float* b1 = (const float*)d_in[3];
    const float* W2 = (const float*)d_in[4];
    const float* b2 = (const float*)d_in[5];
    float* out = (float*)d_out;

    const int* src = ei;
    const int* dst = ei + N_EDGES;

    char* w = (char*)d_ws;
    size_t off = 0;
    int*   cnt     = (int*)(w + off);   off += align_up((size_t)N_NODES * 4);
    int*   fill    = (int*)(w + off);   off += align_up((size_t)N_NODES * 4);
    int*   rowptr  = (int*)(w + off);   off += align_up((size_t)(N_NODES + 1) * 4);
    float* dinv    = (float*)(w + off); off += align_up((size_t)N_NODES * 4);
    int*   bsum    = (int*)(w + off);   off += align_up((size_t)NB_SCAN * 4);
    int*   boff    = (int*)(w + off);   off += align_up((size_t)NB_SCAN * 4);
    int*   csr_src = (int*)(w + off);   off += align_up((size_t)N_EDGES * 4);
    float* h0      = (float*)(w + off); off += align_up((size_t)N_NODES * HIDDEN * 4);
    float* h2      = (float*)(w + off); off += align_up((size_t)N_NODES * OUTC * 4);

    // cnt and fill are adjacent -> one memset clears both
    hipMemsetAsync(cnt, 0, align_up((size_t)N_NODES * 4) + (size_t)N_NODES * 4, stream);

    const int B = 256;
    k_deg    <<<(N_EDGES + B - 1) / B, B, 0, stream>>>(dst, cnt);
    k_scan1  <<<NB_SCAN, B, 0, stream>>>(cnt, rowptr, bsum, dinv);
    k_scan2  <<<1, 512, 0, stream>>>(bsum, boff, rowptr);
    k_scan3  <<<NB_SCAN, B, 0, stream>>>(rowptr, boff);
    k_scatter<<<(N_EDGES + B - 1) / B, B, 0, stream>>>(src, dst, rowptr, fill, csr_src);
    k_gemm1  <<<N_NODES / 8, B, 0, stream>>>(x, W1, h0);
    k_layer1 <<<(N_NODES * HIDDEN + B - 1) / B, B, 0, stream>>>(rowptr, csr_src, dinv, h0, b1, W2, h2);
    k_layer2 <<<(N_NODES + B - 1) / B, B, 0, stream>>>(rowptr, csr_src, dinv, h2, b2, out);
}